// Round 11
// baseline (124.233 us; speedup 1.0000x reference)
//
#include <hip/hip_runtime.h>

#define N_NODES 50000
#define N_EDGES 800000
#define D_FEAT 64

#define NPART 200                 // edge partitions
#define EPP (N_EDGES / NPART)     // 4000 edges per partition (exact)
#define NBINS_F ((N_NODES + 63) / 64)   // 782 fine bins of 64 nodes
#define LCAP 4096                 // LDS list capacity (bin avg 1023, sigma 32)

// ---- K1: per-partition LDS histogram over 782 fine bins. No global atomics.
__global__ __launch_bounds__(1024) void part_hist_kernel(const int* __restrict__ dst,
                                                         int* __restrict__ histBB) {
    __shared__ int h[NBINS_F];
    int t = threadIdx.x, blk = blockIdx.x;
    if (t < NBINS_F) h[t] = 0;
    __syncthreads();
    int base = blk * EPP;
    for (int i = t; i < EPP; i += 1024)
        atomicAdd(&h[dst[base + i] >> 6], 1);
    __syncthreads();
    if (t < NBINS_F) histBB[blk * NBINS_F + t] = h[t];
}

// ---- K3: per-bin exclusive scan over the 200 partitions (one block per bin).
__global__ void col_scan_kernel(const int* __restrict__ histBB,
                                int* __restrict__ baseBB,
                                int* __restrict__ binTot) {
    __shared__ int lds[256];
    int bin = blockIdx.x, t = threadIdx.x;
    int v = (t < NPART) ? histBB[t * NBINS_F + bin] : 0;
    lds[t] = v;
    __syncthreads();
    for (int off = 1; off < 256; off <<= 1) {
        int x = (t >= off) ? lds[t - off] : 0;
        __syncthreads();
        lds[t] += x;
        __syncthreads();
    }
    if (t < NPART) baseBB[t * NBINS_F + bin] = lds[t] - v;
    if (t == 255) binTot[bin] = lds[255];
}

// ---- K2: exclusive scan of 782 bin totals (1 block, 1024 threads).
__global__ __launch_bounds__(1024) void bin_scan_kernel(const int* __restrict__ binTot,
                                                        int* __restrict__ binBase) {
    __shared__ int wsum[16];
    int t = threadIdx.x;
    int v = (t < NBINS_F) ? binTot[t] : 0;
    int lane = t & 63, wave = t >> 6;
    int incl = v;
    #pragma unroll
    for (int o = 1; o < 64; o <<= 1) { int x = __shfl_up(incl, o); if (lane >= o) incl += x; }
    if (lane == 63) wsum[wave] = incl;
    __syncthreads();
    int wbase = 0;
    #pragma unroll
    for (int w = 0; w < 16; ++w) wbase += (w < wave) ? wsum[w] : 0;
    if (t < NBINS_F) binBase[t] = wbase + incl - v;
    if (t == NBINS_F - 1) binBase[NBINS_F] = wbase + incl;
}

// ---- K4: scatter packed (src | dstlow<<16) into fine-bin staging segments.
__global__ __launch_bounds__(1024) void part_scatter_kernel(const int* __restrict__ src,
                                                            const int* __restrict__ dst,
                                                            const int* __restrict__ baseBB,
                                                            const int* __restrict__ binBase,
                                                            unsigned int* __restrict__ staging) {
    __shared__ int cur[NBINS_F];
    int t = threadIdx.x, blk = blockIdx.x;
    if (t < NBINS_F) cur[t] = binBase[t] + baseBB[blk * NBINS_F + t];
    __syncthreads();
    int base = blk * EPP;
    for (int i = t; i < EPP; i += 1024) {
        int d = dst[base + i];
        int bin = d >> 6;
        int pos = atomicAdd(&cur[bin], 1);     // LDS atomic
        staging[pos] = (unsigned int)src[base + i] | ((unsigned int)(d & 63) << 16);
    }
}

// ---- K5a: per-bin counting sort -> global u16 CSR (esorted) + offsets.
__global__ __launch_bounds__(256) void sort_to_csr_kernel(const unsigned int* __restrict__ staging,
                                                          const int* __restrict__ binBase,
                                                          unsigned short* __restrict__ esorted,
                                                          int* __restrict__ offs) {
    __shared__ int cntL[64];
    __shared__ int off[65];
    __shared__ int cur[64];
    __shared__ unsigned short list[LCAP];
    int bin = blockIdx.x, t = threadIdx.x;
    int lo = binBase[bin], hi = binBase[bin + 1];
    int n = hi - lo;
    int nodeLo = bin << 6;

    if (t < 64) cntL[t] = 0;
    __syncthreads();
    for (int i = lo + t; i < hi; i += 256)
        atomicAdd(&cntL[(staging[i] >> 16) & 63], 1);
    __syncthreads();
    if (t < 64) {   // threads 0..63 are exactly wave 0
        int v = cntL[t];
        int incl = v;
        #pragma unroll
        for (int o = 1; o < 64; o <<= 1) { int x = __shfl_up(incl, o); if (t >= o) incl += x; }
        off[t] = incl - v;
        cur[t] = incl - v;
    }
    __syncthreads();
    // per-node offsets to global
    if (t < 64) {
        int node = nodeLo + t;
        if (node < N_NODES) offs[node] = lo + off[t];
    }
    if (bin == NBINS_F - 1 && t == 0) offs[N_NODES] = N_EDGES;

    if (n <= LCAP) {
        for (int i = lo + t; i < hi; i += 256) {
            unsigned int pk = staging[i];
            int p = atomicAdd(&cur[(pk >> 16) & 63], 1);
            list[p] = (unsigned short)pk;
        }
        __syncthreads();
        for (int i = t; i < n; i += 256)
            esorted[lo + i] = list[i];
    } else {
        // statistically unreachable; correct but slower
        for (int i = lo + t; i < hi; i += 256) {
            unsigned int pk = staging[i];
            int p = atomicAdd(&cur[(pk >> 16) & 63], 1);
            esorted[lo + p] = (unsigned short)pk;
        }
    }
}

// ---- K5b: high-occupancy CSR pull. 16 lanes per node, float4 per lane,
// cooperative u16 id load + shfl broadcast, nontemporal out stores.
__global__ __launch_bounds__(256) void csr_pull_kernel(const float* __restrict__ xs,
                                                       const unsigned short* __restrict__ esorted,
                                                       const int* __restrict__ offs,
                                                       float* __restrict__ out) {
    int tid = blockIdx.x * 256 + threadIdx.x;   // grid exactly 50000*16
    int node = tid >> 4;
    int c = tid & 15;
    int beg = offs[node];
    int end = offs[node + 1];
    int deg = end - beg;
    float4 acc = make_float4(0.f, 0.f, 0.f, 0.f);
    for (int j0 = 0; j0 < deg; j0 += 16) {
        int rem = deg - j0;
        int m = rem < 16 ? rem : 16;
        int myid = (c < m) ? (int)__builtin_nontemporal_load(esorted + beg + j0 + c) : 0;
        if (m == 16) {
            #pragma unroll
            for (int k = 0; k < 16; ++k) {
                int s = __shfl(myid, k, 16);
                const float4 v = *reinterpret_cast<const float4*>(xs + s * D_FEAT + c * 4);
                acc.x += v.x; acc.y += v.y; acc.z += v.z; acc.w += v.w;
            }
        } else {
            for (int k = 0; k < m; ++k) {
                int s = __shfl(myid, k, 16);
                const float4 v = *reinterpret_cast<const float4*>(xs + s * D_FEAT + c * 4);
                acc.x += v.x; acc.y += v.y; acc.z += v.z; acc.w += v.w;
            }
        }
    }
    float inv = 1.0f / fmaxf((float)deg, 1.0f);
    float* op = out + (size_t)node * D_FEAT + c * 4;
    __builtin_nontemporal_store(acc.x * inv, op + 0);
    __builtin_nontemporal_store(acc.y * inv, op + 1);
    __builtin_nontemporal_store(acc.z * inv, op + 2);
    __builtin_nontemporal_store(acc.w * inv, op + 3);
}

// ---------------- Fallback (small ws): baseline atomic push ----------------

__global__ void scatter_kernel(const float* __restrict__ xs,
                               const int* __restrict__ src,
                               const int* __restrict__ dst,
                               float* __restrict__ sums,
                               float* __restrict__ counts) {
    int tid = blockIdx.x * blockDim.x + threadIdx.x;
    int e = tid >> 4;
    int c = tid & 15;
    if (e >= N_EDGES) return;
    int s = src[e];
    int d = dst[e];
    const float4 v = *reinterpret_cast<const float4*>(xs + (size_t)s * D_FEAT + c * 4);
    float* outp = sums + (size_t)d * D_FEAT + c * 4;
    atomicAdd(outp + 0, v.x);
    atomicAdd(outp + 1, v.y);
    atomicAdd(outp + 2, v.z);
    atomicAdd(outp + 3, v.w);
    if (c == 0) atomicAdd(counts + d, 1.0f);
}

__global__ void divide_kernel(float* __restrict__ out, const float* __restrict__ counts) {
    int tid = blockIdx.x * blockDim.x + threadIdx.x;
    if (tid >= N_NODES * D_FEAT / 4) return;
    int node = tid >> 4;
    float inv = 1.0f / fmaxf(counts[node], 1.0f);
    float4 v = reinterpret_cast<const float4*>(out)[tid];
    v.x *= inv; v.y *= inv; v.z *= inv; v.w *= inv;
    reinterpret_cast<float4*>(out)[tid] = v;
}

// ---------------- launch ----------------

extern "C" void kernel_launch(void* const* d_in, const int* in_sizes, int n_in,
                              void* d_out, int out_size, void* d_ws, size_t ws_size,
                              hipStream_t stream) {
    const float* xs  = (const float*)d_in[0];
    const int*   src = (const int*)d_in[1];
    const int*   dst = (const int*)d_in[2];
    float* out = (float*)d_out;

    size_t need = (size_t)(2 * NPART * NBINS_F + NBINS_F + (NBINS_F + 1) + (N_NODES + 1)) * sizeof(int)
                + (size_t)N_EDGES * sizeof(unsigned int)
                + (size_t)N_EDGES * sizeof(unsigned short);
    if (ws_size < need) {
        float* counts = (float*)d_ws;
        hipMemsetAsync(out, 0, (size_t)N_NODES * D_FEAT * sizeof(float), stream);
        hipMemsetAsync(counts, 0, (size_t)N_NODES * sizeof(float), stream);
        scatter_kernel<<<(N_EDGES * 16 + 255) / 256, 256, 0, stream>>>(xs, src, dst, out, counts);
        divide_kernel<<<(N_NODES * D_FEAT / 4 + 255) / 256, 256, 0, stream>>>(out, counts);
        return;
    }

    int* ws = (int*)d_ws;
    int* histBB  = ws;                           // NPART*NBINS_F
    int* baseBB  = histBB + NPART * NBINS_F;     // NPART*NBINS_F
    int* binTot  = baseBB + NPART * NBINS_F;     // NBINS_F
    int* binBase = binTot + NBINS_F;             // NBINS_F+1
    int* offs    = binBase + NBINS_F + 1;        // N_NODES+1
    unsigned int* staging = (unsigned int*)(offs + N_NODES + 1);      // N_EDGES u32
    unsigned short* esorted = (unsigned short*)(staging + N_EDGES);   // N_EDGES u16

    part_hist_kernel<<<NPART, 1024, 0, stream>>>(dst, histBB);
    col_scan_kernel<<<NBINS_F, 256, 0, stream>>>(histBB, baseBB, binTot);
    bin_scan_kernel<<<1, 1024, 0, stream>>>(binTot, binBase);
    part_scatter_kernel<<<NPART, 1024, 0, stream>>>(src, dst, baseBB, binBase, staging);
    sort_to_csr_kernel<<<NBINS_F, 256, 0, stream>>>(staging, binBase, esorted, offs);
    csr_pull_kernel<<<(N_NODES * 16) / 256, 256, 0, stream>>>(xs, esorted, offs, out);
}